// Round 6
// baseline (223.707 us; speedup 1.0000x reference)
//
#include <hip/hip_runtime.h>

#define B_   4
#define S_   4096
#define NC   8192
#define C_   512
#define CS   256
#define KTOT 768

typedef __attribute__((ext_vector_type(8))) short short8;
typedef __attribute__((ext_vector_type(4))) float f32x4;
typedef float v2f __attribute__((ext_vector_type(2)));

// fp32 -> bf16 round-to-nearest-even (finite inputs only)
static __device__ __forceinline__ unsigned short f2bf(float x) {
    unsigned u = __builtin_bit_cast(unsigned, x);
    unsigned r = u + 0x7FFFu + ((u >> 16) & 1u);
    return (unsigned short)(r >> 16);
}

// Packed fp32 (VOP3P) — IEEE rounding identical to scalar v_mul/v_add/v_sub.
static __device__ __forceinline__ v2f pk_mul(v2f a, v2f b) {
    v2f d;
    asm("v_pk_mul_f32 %0, %1, %2" : "=v"(d) : "v"(a), "v"(b));
    return d;
}
static __device__ __forceinline__ v2f pk_add(v2f a, v2f b) {
    v2f d;
    asm("v_pk_add_f32 %0, %1, %2" : "=v"(d) : "v"(a), "v"(b));
    return d;
}
static __device__ __forceinline__ v2f pk_sub(v2f a, v2f b) {
    v2f d;
    asm("v_pk_add_f32 %0, %1, %2 neg_lo:[0,1] neg_hi:[0,1]" : "=v"(d) : "v"(a), "v"(b));
    return d;
}

// ---------------- K1: argmin partial over one 1024-pair chunk ----------------
// grid (S/32, 4, B): x=query-block, y=chunk c, z=batch. block 256 = 4 waves.
// Wave qg holds 8 queries in regs; lane scans pairs c*1024 + j*64 + lane
// directly from rxyz (aligned float2 x3, coalesced). r2 in-loop, np association.
__global__ __launch_bounds__(256) void argmin_partial_kernel(
        const float* __restrict__ qxyz, const float* __restrict__ rxyz,
        float* __restrict__ pval, int* __restrict__ pidx) {
    int tid = threadIdx.x;
    int lane = tid & 63;
    int qg = tid >> 6;
    int sblk = blockIdx.x;
    int c = blockIdx.y;
    int b = blockIdx.z;
    int sbase = sblk * 32 + qg * 8;

    v2f qx2[8], qy2[8], qz2[8], q22[8];
    #pragma unroll
    for (int q = 0; q < 8; ++q) {
        const float* qp = qxyz + ((size_t)(b * S_ + sbase + q)) * 3;
        float qx = qp[0], qy = qp[1], qz = qp[2];
        float q2 = __fadd_rn(__fadd_rn(__fmul_rn(qx, qx), __fmul_rn(qy, qy)),
                             __fmul_rn(qz, qz));
        qx2[q] = (v2f){qx, qx};
        qy2[q] = (v2f){qy, qy};
        qz2[q] = (v2f){qz, qz};
        q22[q] = (v2f){q2, q2};
    }

    const float* rp = rxyz + ((size_t)b * NC + 2 * (c * 1024 + lane)) * 3;
    float be[8], bo[8];
    int pe[8], po[8];
    #pragma unroll
    for (int q = 0; q < 8; ++q) {
        be[q] = 3.4028235e38f; bo[q] = 3.4028235e38f; pe[q] = 0; po[q] = 0;
    }

    #pragma unroll 4
    for (int j = 0; j < 16; ++j) {
        const float* jp = rp + j * 384;          // 64 pairs * 6 floats
        float2 v1 = *(const float2*)(jp + 0);    // x0 y0
        float2 v2 = *(const float2*)(jp + 2);    // z0 x1
        float2 v3 = *(const float2*)(jp + 4);    // y1 z1
        v2f xs = {v1.x, v2.y}, ys = {v1.y, v3.x}, zs = {v2.x, v3.y};
        // r2 = (x*x + y*y) + z*z — np association, packed IEEE ops
        v2f ws = pk_add(pk_add(pk_mul(xs, xs), pk_mul(ys, ys)), pk_mul(zs, zs));
        #pragma unroll
        for (int q = 0; q < 8; ++q) {
            v2f qr = pk_add(pk_add(pk_mul(qx2[q], xs), pk_mul(qy2[q], ys)),
                            pk_mul(qz2[q], zs));
            v2f d2 = pk_sub(pk_add(q22[q], ws), pk_add(qr, qr));
            if (d2.x < be[q]) { be[q] = d2.x; pe[q] = j; }   // strict <: first occurrence
            if (d2.y < bo[q]) { bo[q] = d2.y; po[q] = j; }
        }
    }

    __shared__ float sv[64][33];   // [lane][query] — transposed, padded
    __shared__ int   sx[64][33];
    #pragma unroll
    for (int q = 0; q < 8; ++q) {
        int ie = (c * 1024 + pe[q] * 64 + lane) * 2;
        int io = (c * 1024 + po[q] * 64 + lane) * 2 + 1;
        float bv; int bx;
        if (bo[q] < be[q] || (bo[q] == be[q] && io < ie)) { bv = bo[q]; bx = io; }
        else                                              { bv = be[q]; bx = ie; }
        sv[lane][qg * 8 + q] = bv;
        sx[lane][qg * 8 + q] = bx;
    }
    __syncthreads();
    if (tid < 32) {
        float v = sv[0][tid];
        int x = sx[0][tid];
        #pragma unroll 8
        for (int l = 1; l < 64; ++l) {
            float vv = sv[l][tid];
            int xx = sx[l][tid];
            // interleaved lanes within chunk: (val, idx) tiebreak = first occurrence
            if (vv < v || (vv == v && xx < x)) { v = vv; x = xx; }
        }
        int qs = b * S_ + sblk * 32 + tid;
        pval[qs * 4 + c] = v;
        pidx[qs * 4 + c] = x;
    }
}

// ---------------- K2: transpose ref_feat (B,C,Nc) fp32 -> refT (B,Nc,C) bf16 ----------------
__global__ __launch_bounds__(256) void transpose_kernel(const float* __restrict__ rf,
                                                        unsigned short* __restrict__ refT) {
    __shared__ float t[64][65];
    int tid = threadIdx.x;
    int b = blockIdx.z;
    int c0 = blockIdx.y * 64;
    int n0 = blockIdx.x * 64;
    int tx = tid & 15, ty = tid >> 4;
    #pragma unroll
    for (int r = 0; r < 4; ++r) {
        int c = r * 16 + ty;
        float4 v = *(const float4*)(rf + ((size_t)b * C_ + c0 + c) * NC + n0 + tx * 4);
        t[tx * 4 + 0][c] = v.x;
        t[tx * 4 + 1][c] = v.y;
        t[tx * 4 + 2][c] = v.z;
        t[tx * 4 + 3][c] = v.w;
    }
    __syncthreads();
    #pragma unroll
    for (int r = 0; r < 4; ++r) {
        int n = r * 16 + ty;
        ushort4 o;
        o.x = f2bf(t[n][tx * 4 + 0]);
        o.y = f2bf(t[n][tx * 4 + 1]);
        o.z = f2bf(t[n][tx * 4 + 2]);
        o.w = f2bf(t[n][tx * 4 + 3]);
        *(ushort4*)(refT + ((size_t)b * NC + n0 + n) * C_ + c0 + tx * 4) = o;
    }
}

// ---------------- K3a: Wc = W_concat[:,256:] @ W_seed -> Wcomb cols 256..767 ----------------
__global__ __launch_bounds__(256) void wc_kernel(const float* __restrict__ Wcat,
                                                 const float* __restrict__ Wseed,
                                                 unsigned short* __restrict__ Wcomb) {
    __shared__ float sa[64][68];
    __shared__ float sbt[64][68];
    int tid = threadIdx.x;
    int to = blockIdx.y * 64;
    int tc = blockIdx.x * 64;
    int tx = tid & 15, ty = tid >> 4;
    float acc[4][4] = {};
    for (int kt = 0; kt < 256; kt += 64) {
        __syncthreads();
        #pragma unroll
        for (int r = 0; r < 4; ++r) {
            int oo = r * 16 + ty;
            float4 v = *(const float4*)(Wcat + (size_t)(to + oo) * 512 + 256 + kt + tx * 4);
            sa[oo][tx * 4 + 0] = v.x;
            sa[oo][tx * 4 + 1] = v.y;
            sa[oo][tx * 4 + 2] = v.z;
            sa[oo][tx * 4 + 3] = v.w;
            float4 u = *(const float4*)(Wseed + (size_t)(kt + oo) * 512 + tc + tx * 4);
            sbt[oo][tx * 4 + 0] = u.x;
            sbt[oo][tx * 4 + 1] = u.y;
            sbt[oo][tx * 4 + 2] = u.z;
            sbt[oo][tx * 4 + 3] = u.w;
        }
        __syncthreads();
        for (int k = 0; k < 64; ++k) {
            float a[4], bb[4];
            #pragma unroll
            for (int i = 0; i < 4; ++i) a[i] = sa[ty * 4 + i][k];
            #pragma unroll
            for (int j = 0; j < 4; ++j) bb[j] = sbt[k][tx * 4 + j];
            #pragma unroll
            for (int i = 0; i < 4; ++i)
                #pragma unroll
                for (int j = 0; j < 4; ++j)
                    acc[i][j] = fmaf(a[i], bb[j], acc[i][j]);
        }
    }
    #pragma unroll
    for (int i = 0; i < 4; ++i)
        #pragma unroll
        for (int j = 0; j < 4; ++j)
            Wcomb[(size_t)(to + ty * 4 + i) * KTOT + 256 + tc + tx * 4 + j] = f2bf(acc[i][j]);
}

// ---------------- K3b: W1 = W_concat[:, :256] -> Wcomb cols 0..255 ----------------
__global__ __launch_bounds__(256) void w1_kernel(const float* __restrict__ Wcat,
                                                 unsigned short* __restrict__ Wcomb) {
    int gid = blockIdx.x * 256 + threadIdx.x;  // 65536
    int o = gid >> 8, c = gid & 255;
    Wcomb[(size_t)o * KTOT + c] = f2bf(Wcat[(size_t)o * 512 + c]);
}

// ---------------- K3c: b_eff = W2 @ b_seed + b_concat ----------------
__global__ __launch_bounds__(256) void beff_kernel(const float* __restrict__ Wcat,
                                                   const float* __restrict__ bseed,
                                                   const float* __restrict__ bcat,
                                                   float* __restrict__ beff) {
    int o = threadIdx.x;
    float acc = bcat[o];
    const float4* wp = (const float4*)(Wcat + (size_t)o * 512 + 256);
    const float4* bp = (const float4*)bseed;
    #pragma unroll 4
    for (int j = 0; j < 64; ++j) {
        float4 w = wp[j];
        float4 bb = bp[j];
        acc = fmaf(w.x, bb.x, acc);
        acc = fmaf(w.y, bb.y, acc);
        acc = fmaf(w.z, bb.z, acc);
        acc = fmaf(w.w, bb.w, acc);
    }
    beff[o] = acc;
}

// ---------------- K4: fused merge + gather + GEMM ----------------
// out[b](256 x 4096) = Wcomb(256x768) @ X(768x4096) + b_eff
// block tile 128(M) x 32(N), BK=64, 4 waves. grid (128, 2, 4)
__global__ __launch_bounds__(256) void fused_gemm_kernel(
        const unsigned short* __restrict__ Wcomb,
        const float* __restrict__ seed,
        const unsigned short* __restrict__ refT,
        const float* __restrict__ pval,
        const int* __restrict__ pidx,
        const float* __restrict__ beff,
        float* __restrict__ out) {
    __shared__ __align__(16) unsigned short sA[128][72];
    __shared__ __align__(16) unsigned short sB[32][72];
    __shared__ int sIdx[32];
    __shared__ float sBias[128];

    int tid = threadIdx.x;
    int b = blockIdx.z;
    int m0 = blockIdx.y * 128;
    int s0 = blockIdx.x * 32;
    if (tid < 32) {
        // merge 4 chunk-partials; disjoint ascending index ranges -> (val,idx) min
        int qs = b * S_ + s0 + tid;
        float v = pval[qs * 4 + 0];
        int x = pidx[qs * 4 + 0];
        #pragma unroll
        for (int c = 1; c < 4; ++c) {
            float vv = pval[qs * 4 + c];
            int xx = pidx[qs * 4 + c];
            if (vv < v || (vv == v && xx < x)) { v = vv; x = xx; }
        }
        sIdx[tid] = x & (NC - 1);   // defensive clamp: OOB gather impossible
    }
    if (tid < 128) sBias[tid] = beff[m0 + tid];

    int lane = tid & 63;
    int w = tid >> 6;
    int ln = lane & 15;
    int quad = lane >> 4;
    int q8 = quad * 8;

    f32x4 acc[2][2];
    #pragma unroll
    for (int i = 0; i < 2; ++i)
        #pragma unroll
        for (int j = 0; j < 2; ++j)
            acc[i][j] = (f32x4){0.f, 0.f, 0.f, 0.f};

    for (int ks = 0; ks < 12; ++ks) {
        int k0 = ks * 64;
        __syncthreads();
        #pragma unroll
        for (int i = 0; i < 4; ++i) {
            int ch = tid + 256 * i;
            int mm = ch >> 3;
            int kk8 = (ch & 7) << 3;
            *(short8*)&sA[mm][kk8] =
                *(const short8*)(Wcomb + (size_t)(m0 + mm) * KTOT + k0 + kk8);
        }
        if (k0 < 256) {
            int n = tid & 31;
            int kk8 = (tid >> 5) << 3;
            const float* sp = seed + ((size_t)b * CS + k0 + kk8) * S_ + s0 + n;
            unsigned short tmp[8];
            #pragma unroll
            for (int r = 0; r < 8; ++r)
                tmp[r] = f2bf(sp[(size_t)r * S_]);
            *(short8*)&sB[n][kk8] = *(const short8*)tmp;
        } else {
            int n = tid >> 3;
            int kk8 = (tid & 7) << 3;
            const unsigned short* gp =
                refT + ((size_t)b * NC + sIdx[n]) * C_ + (k0 - 256) + kk8;
            *(short8*)&sB[n][kk8] = *(const short8*)gp;
        }
        __syncthreads();
        #pragma unroll
        for (int kf = 0; kf < 2; ++kf) {
            short8 af[2], bfr[2];
            #pragma unroll
            for (int i = 0; i < 2; ++i)
                af[i] = *(const short8*)&sA[w * 32 + i * 16 + ln][kf * 32 + q8];
            #pragma unroll
            for (int j = 0; j < 2; ++j)
                bfr[j] = *(const short8*)&sB[j * 16 + ln][kf * 32 + q8];
            #pragma unroll
            for (int i = 0; i < 2; ++i)
                #pragma unroll
                for (int j = 0; j < 2; ++j)
                    acc[i][j] = __builtin_amdgcn_mfma_f32_16x16x32_bf16(af[i], bfr[j], acc[i][j], 0, 0, 0);
        }
    }

    #pragma unroll
    for (int i = 0; i < 2; ++i) {
        int mb = w * 32 + i * 16 + quad * 4;
        #pragma unroll
        for (int j = 0; j < 2; ++j) {
            int col = s0 + j * 16 + ln;
            #pragma unroll
            for (int r = 0; r < 4; ++r) {
                int m = mb + r;
                out[((size_t)b * CS + m0 + m) * S_ + col] = acc[i][j][r] + sBias[m];
            }
        }
    }
}

extern "C" void kernel_launch(void* const* d_in, const int* in_sizes, int n_in,
                              void* d_out, int out_size, void* d_ws, size_t ws_size,
                              hipStream_t stream) {
    const float* qxyz  = (const float*)d_in[0];
    const float* rxyz  = (const float*)d_in[1];
    const float* rfeat = (const float*)d_in[2];
    const float* seed  = (const float*)d_in[3];
    const float* Wseed = (const float*)d_in[4];
    const float* bseed = (const float*)d_in[5];
    const float* Wcat  = (const float*)d_in[6];
    const float* bcat  = (const float*)d_in[7];
    float* out = (float*)d_out;

    char* ws = (char*)d_ws;
    float* pval           = (float*)(ws);                        // 256 KB
    int* pidx             = (int*)(ws + 262144);                 // 256 KB
    float* beff           = (float*)(ws + 524288);               // 1 KB
    unsigned short* Wcomb = (unsigned short*)(ws + 525312);      // 384 KB
    unsigned short* refT  = (unsigned short*)(ws + 1048576);     // 32 MB

    hipLaunchKernelGGL(argmin_partial_kernel, dim3(128, 4, 4), dim3(256), 0, stream,
                       qxyz, rxyz, pval, pidx);
    hipLaunchKernelGGL(transpose_kernel,      dim3(128, 8, 4), dim3(256), 0, stream, rfeat, refT);
    hipLaunchKernelGGL(wc_kernel,             dim3(8, 4),      dim3(256), 0, stream, Wcat, Wseed, Wcomb);
    hipLaunchKernelGGL(w1_kernel,             dim3(256),       dim3(256), 0, stream, Wcat, Wcomb);
    hipLaunchKernelGGL(beff_kernel,           dim3(1),         dim3(256), 0, stream, Wcat, bseed, bcat, beff);
    hipLaunchKernelGGL(fused_gemm_kernel,     dim3(128, 2, 4), dim3(256), 0, stream,
                       Wcomb, seed, refT, pval, pidx, beff, out);
}

// Round 8
// 220.343 us; speedup vs baseline: 1.0153x; 1.0153x over previous
//
#include <hip/hip_runtime.h>

#define B_   4
#define S_   4096
#define NC   8192
#define C_   512
#define CS   256
#define KTOT 768

typedef __attribute__((ext_vector_type(8))) short short8;
typedef __attribute__((ext_vector_type(4))) float f32x4;

// fp32 -> bf16 round-to-nearest-even (finite inputs only)
static __device__ __forceinline__ unsigned short f2bf(float x) {
    unsigned u = __builtin_bit_cast(unsigned, x);
    unsigned r = u + 0x7FFFu + ((u >> 16) & 1u);
    return (unsigned short)(r >> 16);
}

// ---------------- K1: argmin partial over one 2048-ref chunk ----------------
// grid (S/32, 4, B): x=query-block, y=chunk c, z=batch. block 256 = 4 waves.
// Wave qg holds 8 queries as SCALARS (32 VGPRs, no spill — R6's pk version
// spilled at VGPR=68); lane scans refs e = c*2048 + j*64 + lane, j=0..31,
// directly from rxyz (coalesced, stride 64 refs). Scalar IEEE ops, np
// association — packed f32 is half-rate per element on CDNA4, so scalar
// costs identical VALU time at half the register pressure.
__global__ __launch_bounds__(256) void argmin_partial_kernel(
        const float* __restrict__ qxyz, const float* __restrict__ rxyz,
        float* __restrict__ pval, int* __restrict__ pidx) {
    int tid = threadIdx.x;
    int lane = tid & 63;
    int qg = tid >> 6;
    int sblk = blockIdx.x;
    int c = blockIdx.y;
    int b = blockIdx.z;
    int sbase = sblk * 32 + qg * 8;

    float qx[8], qy[8], qz[8], q2[8];
    #pragma unroll
    for (int q = 0; q < 8; ++q) {
        const float* qp = qxyz + ((size_t)(b * S_ + sbase + q)) * 3;
        qx[q] = qp[0]; qy[q] = qp[1]; qz[q] = qp[2];
        q2[q] = __fadd_rn(__fadd_rn(__fmul_rn(qx[q], qx[q]), __fmul_rn(qy[q], qy[q])),
                          __fmul_rn(qz[q], qz[q]));
    }

    const float* ep = rxyz + ((size_t)b * NC + c * 2048 + lane) * 3;
    float best[8];
    int bj[8];
    #pragma unroll
    for (int q = 0; q < 8; ++q) { best[q] = 3.4028235e38f; bj[q] = 0; }

    #pragma unroll 2
    for (int j = 0; j < 32; ++j) {
        const float* jp = ep + j * 192;   // 64 refs * 3 floats
        float x = jp[0], y = jp[1], z = jp[2];
        // r2 = (x*x + y*y) + z*z — np association
        float r2 = __fadd_rn(__fadd_rn(__fmul_rn(x, x), __fmul_rn(y, y)),
                             __fmul_rn(z, z));
        #pragma unroll
        for (int q = 0; q < 8; ++q) {
            // qr = ((qx*rx + qy*ry) + qz*rz), no FMA
            float qr = __fadd_rn(__fadd_rn(__fmul_rn(qx[q], x), __fmul_rn(qy[q], y)),
                                 __fmul_rn(qz[q], z));
            // d2 = (q2 + r2) - (qr + qr); 2*qr exact
            float d2 = __fsub_rn(__fadd_rn(q2[q], r2), __fadd_rn(qr, qr));
            if (d2 < best[q]) { best[q] = d2; bj[q] = j; }   // strict <: first occurrence per lane
        }
    }

    __shared__ float sv[64][33];   // [lane][query] — transposed, padded
    __shared__ int   sx[64][33];
    #pragma unroll
    for (int q = 0; q < 8; ++q) {
        sv[lane][qg * 8 + q] = best[q];
        sx[lane][qg * 8 + q] = c * 2048 + bj[q] * 64 + lane;
    }
    __syncthreads();
    if (tid < 32) {
        float v = sv[0][tid];
        int x = sx[0][tid];
        #pragma unroll 8
        for (int l = 1; l < 64; ++l) {
            float vv = sv[l][tid];
            int xx = sx[l][tid];
            // lanes interleave indices: (val, idx) tiebreak = first occurrence
            if (vv < v || (vv == v && xx < x)) { v = vv; x = xx; }
        }
        int qs = b * S_ + sblk * 32 + tid;
        pval[qs * 4 + c] = v;
        pidx[qs * 4 + c] = x;
    }
}

// ---------------- K2: transpose ref_feat (B,C,Nc) fp32 -> refT (B,Nc,C) bf16 ----------------
__global__ __launch_bounds__(256) void transpose_kernel(const float* __restrict__ rf,
                                                        unsigned short* __restrict__ refT) {
    __shared__ float t[64][65];
    int tid = threadIdx.x;
    int b = blockIdx.z;
    int c0 = blockIdx.y * 64;
    int n0 = blockIdx.x * 64;
    int tx = tid & 15, ty = tid >> 4;
    #pragma unroll
    for (int r = 0; r < 4; ++r) {
        int c = r * 16 + ty;
        float4 v = *(const float4*)(rf + ((size_t)b * C_ + c0 + c) * NC + n0 + tx * 4);
        t[tx * 4 + 0][c] = v.x;
        t[tx * 4 + 1][c] = v.y;
        t[tx * 4 + 2][c] = v.z;
        t[tx * 4 + 3][c] = v.w;
    }
    __syncthreads();
    #pragma unroll
    for (int r = 0; r < 4; ++r) {
        int n = r * 16 + ty;
        ushort4 o;
        o.x = f2bf(t[n][tx * 4 + 0]);
        o.y = f2bf(t[n][tx * 4 + 1]);
        o.z = f2bf(t[n][tx * 4 + 2]);
        o.w = f2bf(t[n][tx * 4 + 3]);
        *(ushort4*)(refT + ((size_t)b * NC + n0 + n) * C_ + c0 + tx * 4) = o;
    }
}

// ---------------- K3a: Wc = W_concat[:,256:] @ W_seed -> Wcomb cols 256..767 ----------------
__global__ __launch_bounds__(256) void wc_kernel(const float* __restrict__ Wcat,
                                                 const float* __restrict__ Wseed,
                                                 unsigned short* __restrict__ Wcomb) {
    __shared__ float sa[64][68];
    __shared__ float sbt[64][68];
    int tid = threadIdx.x;
    int to = blockIdx.y * 64;
    int tc = blockIdx.x * 64;
    int tx = tid & 15, ty = tid >> 4;
    float acc[4][4] = {};
    for (int kt = 0; kt < 256; kt += 64) {
        __syncthreads();
        #pragma unroll
        for (int r = 0; r < 4; ++r) {
            int oo = r * 16 + ty;
            float4 v = *(const float4*)(Wcat + (size_t)(to + oo) * 512 + 256 + kt + tx * 4);
            sa[oo][tx * 4 + 0] = v.x;
            sa[oo][tx * 4 + 1] = v.y;
            sa[oo][tx * 4 + 2] = v.z;
            sa[oo][tx * 4 + 3] = v.w;
            float4 u = *(const float4*)(Wseed + (size_t)(kt + oo) * 512 + tc + tx * 4);
            sbt[oo][tx * 4 + 0] = u.x;
            sbt[oo][tx * 4 + 1] = u.y;
            sbt[oo][tx * 4 + 2] = u.z;
            sbt[oo][tx * 4 + 3] = u.w;
        }
        __syncthreads();
        for (int k = 0; k < 64; ++k) {
            float a[4], bb[4];
            #pragma unroll
            for (int i = 0; i < 4; ++i) a[i] = sa[ty * 4 + i][k];
            #pragma unroll
            for (int j = 0; j < 4; ++j) bb[j] = sbt[k][tx * 4 + j];
            #pragma unroll
            for (int i = 0; i < 4; ++i)
                #pragma unroll
                for (int j = 0; j < 4; ++j)
                    acc[i][j] = fmaf(a[i], bb[j], acc[i][j]);
        }
    }
    #pragma unroll
    for (int i = 0; i < 4; ++i)
        #pragma unroll
        for (int j = 0; j < 4; ++j)
            Wcomb[(size_t)(to + ty * 4 + i) * KTOT + 256 + tc + tx * 4 + j] = f2bf(acc[i][j]);
}

// ---------------- K3b: W1 = W_concat[:, :256] -> Wcomb cols 0..255 ----------------
__global__ __launch_bounds__(256) void w1_kernel(const float* __restrict__ Wcat,
                                                 unsigned short* __restrict__ Wcomb) {
    int gid = blockIdx.x * 256 + threadIdx.x;  // 65536
    int o = gid >> 8, c = gid & 255;
    Wcomb[(size_t)o * KTOT + c] = f2bf(Wcat[(size_t)o * 512 + c]);
}

// ---------------- K3c: b_eff = W2 @ b_seed + b_concat ----------------
__global__ __launch_bounds__(256) void beff_kernel(const float* __restrict__ Wcat,
                                                   const float* __restrict__ bseed,
                                                   const float* __restrict__ bcat,
                                                   float* __restrict__ beff) {
    int o = threadIdx.x;
    float acc = bcat[o];
    const float4* wp = (const float4*)(Wcat + (size_t)o * 512 + 256);
    const float4* bp = (const float4*)bseed;
    #pragma unroll 4
    for (int j = 0; j < 64; ++j) {
        float4 w = wp[j];
        float4 bb = bp[j];
        acc = fmaf(w.x, bb.x, acc);
        acc = fmaf(w.y, bb.y, acc);
        acc = fmaf(w.z, bb.z, acc);
        acc = fmaf(w.w, bb.w, acc);
    }
    beff[o] = acc;
}

// ---------------- K4: fused merge + gather + GEMM ----------------
// out[b](256 x 4096) = Wcomb(256x768) @ X(768x4096) + b_eff
// block tile 128(M) x 32(N), BK=64, 4 waves. grid (128, 2, 4)
__global__ __launch_bounds__(256) void fused_gemm_kernel(
        const unsigned short* __restrict__ Wcomb,
        const float* __restrict__ seed,
        const unsigned short* __restrict__ refT,
        const float* __restrict__ pval,
        const int* __restrict__ pidx,
        const float* __restrict__ beff,
        float* __restrict__ out) {
    __shared__ __align__(16) unsigned short sA[128][72];
    __shared__ __align__(16) unsigned short sB[32][72];
    __shared__ int sIdx[32];
    __shared__ float sBias[128];

    int tid = threadIdx.x;
    int b = blockIdx.z;
    int m0 = blockIdx.y * 128;
    int s0 = blockIdx.x * 32;
    if (tid < 32) {
        // merge 4 chunk-partials; disjoint ascending index ranges -> (val,idx) min
        int qs = b * S_ + s0 + tid;
        float v = pval[qs * 4 + 0];
        int x = pidx[qs * 4 + 0];
        #pragma unroll
        for (int c = 1; c < 4; ++c) {
            float vv = pval[qs * 4 + c];
            int xx = pidx[qs * 4 + c];
            if (vv < v || (vv == v && xx < x)) { v = vv; x = xx; }
        }
        sIdx[tid] = x & (NC - 1);   // defensive clamp: OOB gather impossible
    }
    if (tid < 128) sBias[tid] = beff[m0 + tid];

    int lane = tid & 63;
    int w = tid >> 6;
    int ln = lane & 15;
    int quad = lane >> 4;
    int q8 = quad * 8;

    f32x4 acc[2][2];
    #pragma unroll
    for (int i = 0; i < 2; ++i)
        #pragma unroll
        for (int j = 0; j < 2; ++j)
            acc[i][j] = (f32x4){0.f, 0.f, 0.f, 0.f};

    for (int ks = 0; ks < 12; ++ks) {
        int k0 = ks * 64;
        __syncthreads();
        #pragma unroll
        for (int i = 0; i < 4; ++i) {
            int ch = tid + 256 * i;
            int mm = ch >> 3;
            int kk8 = (ch & 7) << 3;
            *(short8*)&sA[mm][kk8] =
                *(const short8*)(Wcomb + (size_t)(m0 + mm) * KTOT + k0 + kk8);
        }
        if (k0 < 256) {
            int n = tid & 31;
            int kk8 = (tid >> 5) << 3;
            const float* sp = seed + ((size_t)b * CS + k0 + kk8) * S_ + s0 + n;
            unsigned short tmp[8];
            #pragma unroll
            for (int r = 0; r < 8; ++r)
                tmp[r] = f2bf(sp[(size_t)r * S_]);
            *(short8*)&sB[n][kk8] = *(const short8*)tmp;
        } else {
            int n = tid >> 3;
            int kk8 = (tid & 7) << 3;
            const unsigned short* gp =
                refT + ((size_t)b * NC + sIdx[n]) * C_ + (k0 - 256) + kk8;
            *(short8*)&sB[n][kk8] = *(const short8*)gp;
        }
        __syncthreads();
        #pragma unroll
        for (int kf = 0; kf < 2; ++kf) {
            short8 af[2], bfr[2];
            #pragma unroll
            for (int i = 0; i < 2; ++i)
                af[i] = *(const short8*)&sA[w * 32 + i * 16 + ln][kf * 32 + q8];
            #pragma unroll
            for (int j = 0; j < 2; ++j)
                bfr[j] = *(const short8*)&sB[j * 16 + ln][kf * 32 + q8];
            #pragma unroll
            for (int i = 0; i < 2; ++i)
                #pragma unroll
                for (int j = 0; j < 2; ++j)
                    acc[i][j] = __builtin_amdgcn_mfma_f32_16x16x32_bf16(af[i], bfr[j], acc[i][j], 0, 0, 0);
        }
    }

    #pragma unroll
    for (int i = 0; i < 2; ++i) {
        int mb = w * 32 + i * 16 + quad * 4;
        #pragma unroll
        for (int j = 0; j < 2; ++j) {
            int col = s0 + j * 16 + ln;
            #pragma unroll
            for (int r = 0; r < 4; ++r) {
                int m = mb + r;
                out[((size_t)b * CS + m0 + m) * S_ + col] = acc[i][j][r] + sBias[m];
            }
        }
    }
}

extern "C" void kernel_launch(void* const* d_in, const int* in_sizes, int n_in,
                              void* d_out, int out_size, void* d_ws, size_t ws_size,
                              hipStream_t stream) {
    const float* qxyz  = (const float*)d_in[0];
    const float* rxyz  = (const float*)d_in[1];
    const float* rfeat = (const float*)d_in[2];
    const float* seed  = (const float*)d_in[3];
    const float* Wseed = (const float*)d_in[4];
    const float* bseed = (const float*)d_in[5];
    const float* Wcat  = (const float*)d_in[6];
    const float* bcat  = (const float*)d_in[7];
    float* out = (float*)d_out;

    char* ws = (char*)d_ws;
    float* pval           = (float*)(ws);                        // 256 KB
    int* pidx             = (int*)(ws + 262144);                 // 256 KB
    float* beff           = (float*)(ws + 524288);               // 1 KB
    unsigned short* Wcomb = (unsigned short*)(ws + 525312);      // 384 KB
    unsigned short* refT  = (unsigned short*)(ws + 1048576);     // 32 MB

    hipLaunchKernelGGL(argmin_partial_kernel, dim3(128, 4, 4), dim3(256), 0, stream,
                       qxyz, rxyz, pval, pidx);
    hipLaunchKernelGGL(transpose_kernel,      dim3(128, 8, 4), dim3(256), 0, stream, rfeat, refT);
    hipLaunchKernelGGL(wc_kernel,             dim3(8, 4),      dim3(256), 0, stream, Wcat, Wseed, Wcomb);
    hipLaunchKernelGGL(w1_kernel,             dim3(256),       dim3(256), 0, stream, Wcat, Wcomb);
    hipLaunchKernelGGL(beff_kernel,           dim3(1),         dim3(256), 0, stream, Wcat, bseed, bcat, beff);
    hipLaunchKernelGGL(fused_gemm_kernel,     dim3(128, 2, 4), dim3(256), 0, stream,
                       Wcomb, seed, refT, pval, pidx, beff, out);
}

// Round 9
// 213.315 us; speedup vs baseline: 1.0487x; 1.0329x over previous
//
#include <hip/hip_runtime.h>

#define B_   4
#define S_   4096
#define NC   8192
#define C_   512
#define CS   256
#define KTOT 768

typedef __attribute__((ext_vector_type(8))) short short8;
typedef __attribute__((ext_vector_type(4))) float f32x4;

// fp32 -> bf16 round-to-nearest-even (finite inputs only)
static __device__ __forceinline__ unsigned short f2bf(float x) {
    unsigned u = __builtin_bit_cast(unsigned, x);
    unsigned r = u + 0x7FFFu + ((u >> 16) & 1u);
    return (unsigned short)(r >> 16);
}

// ---------------- K0: pack refs as float4 {x,y,z,r2} ----------------
// r2 = (x*x + y*y) + z*z, no FMA — np association. (R1-proven kernel.)
__global__ __launch_bounds__(256) void pad_ref_kernel(const float* __restrict__ rxyz,
                                                      float4* __restrict__ refpk) {
    int gid = blockIdx.x * 256 + threadIdx.x;  // 0..32767 (B*NC)
    float x = rxyz[gid * 3 + 0];
    float y = rxyz[gid * 3 + 1];
    float z = rxyz[gid * 3 + 2];
    float r2 = __fadd_rn(__fadd_rn(__fmul_rn(x, x), __fmul_rn(y, y)), __fmul_rn(z, z));
    refpk[gid] = make_float4(x, y, z, r2);
}

// ---------------- K1: argmin partial over one 2048-ref chunk ----------------
// grid (S/32, 4, B). block 256 = 4 waves; wave qg holds 8 queries as scalars;
// lane scans refs e = c*2048 + j*64 + lane, j=0..31, one dwordx4 per ref
// (r2 precomputed). Scalar IEEE ops, exact np association.
__global__ __launch_bounds__(256) void argmin_partial_kernel(
        const float* __restrict__ qxyz, const float4* __restrict__ refpk,
        float* __restrict__ pval, int* __restrict__ pidx) {
    int tid = threadIdx.x;
    int lane = tid & 63;
    int qg = tid >> 6;
    int sblk = blockIdx.x;
    int c = blockIdx.y;
    int b = blockIdx.z;
    int sbase = sblk * 32 + qg * 8;

    float qx[8], qy[8], qz[8], q2[8];
    #pragma unroll
    for (int q = 0; q < 8; ++q) {
        const float* qp = qxyz + ((size_t)(b * S_ + sbase + q)) * 3;
        qx[q] = qp[0]; qy[q] = qp[1]; qz[q] = qp[2];
        q2[q] = __fadd_rn(__fadd_rn(__fmul_rn(qx[q], qx[q]), __fmul_rn(qy[q], qy[q])),
                          __fmul_rn(qz[q], qz[q]));
    }

    const float4* ep = refpk + (size_t)b * NC + c * 2048 + lane;
    float best[8];
    int bj[8];
    #pragma unroll
    for (int q = 0; q < 8; ++q) { best[q] = 3.4028235e38f; bj[q] = 0; }

    #pragma unroll 4
    for (int j = 0; j < 32; ++j) {
        float4 r = ep[j * 64];
        #pragma unroll
        for (int q = 0; q < 8; ++q) {
            // qr = ((qx*rx + qy*ry) + qz*rz), no FMA
            float qr = __fadd_rn(__fadd_rn(__fmul_rn(qx[q], r.x), __fmul_rn(qy[q], r.y)),
                                 __fmul_rn(qz[q], r.z));
            // d2 = (q2 + r2) - (qr + qr); 2*qr exact
            float d2 = __fsub_rn(__fadd_rn(q2[q], r.w), __fadd_rn(qr, qr));
            if (d2 < best[q]) { best[q] = d2; bj[q] = j; }   // strict <: first occurrence per lane
        }
    }

    __shared__ float sv[64][33];   // [lane][query] — transposed, padded
    __shared__ int   sx[64][33];
    #pragma unroll
    for (int q = 0; q < 8; ++q) {
        sv[lane][qg * 8 + q] = best[q];
        sx[lane][qg * 8 + q] = c * 2048 + bj[q] * 64 + lane;
    }
    __syncthreads();
    if (tid < 32) {
        float v = sv[0][tid];
        int x = sx[0][tid];
        #pragma unroll 8
        for (int l = 1; l < 64; ++l) {
            float vv = sv[l][tid];
            int xx = sx[l][tid];
            // lanes interleave indices: (val, idx) tiebreak = first occurrence
            if (vv < v || (vv == v && xx < x)) { v = vv; x = xx; }
        }
        int qs = b * S_ + sblk * 32 + tid;
        pval[qs * 4 + c] = v;
        pidx[qs * 4 + c] = x;
    }
}

// ---------------- K2: transpose ref_feat (B,C,Nc) fp32 -> refT (B,Nc,C) bf16 ----------------
__global__ __launch_bounds__(256) void transpose_kernel(const float* __restrict__ rf,
                                                        unsigned short* __restrict__ refT) {
    __shared__ float t[64][65];
    int tid = threadIdx.x;
    int b = blockIdx.z;
    int c0 = blockIdx.y * 64;
    int n0 = blockIdx.x * 64;
    int tx = tid & 15, ty = tid >> 4;
    #pragma unroll
    for (int r = 0; r < 4; ++r) {
        int c = r * 16 + ty;
        float4 v = *(const float4*)(rf + ((size_t)b * C_ + c0 + c) * NC + n0 + tx * 4);
        t[tx * 4 + 0][c] = v.x;
        t[tx * 4 + 1][c] = v.y;
        t[tx * 4 + 2][c] = v.z;
        t[tx * 4 + 3][c] = v.w;
    }
    __syncthreads();
    #pragma unroll
    for (int r = 0; r < 4; ++r) {
        int n = r * 16 + ty;
        ushort4 o;
        o.x = f2bf(t[n][tx * 4 + 0]);
        o.y = f2bf(t[n][tx * 4 + 1]);
        o.z = f2bf(t[n][tx * 4 + 2]);
        o.w = f2bf(t[n][tx * 4 + 3]);
        *(ushort4*)(refT + ((size_t)b * NC + n0 + n) * C_ + c0 + tx * 4) = o;
    }
}

// ---------------- K3a: Wc = W_concat[:,256:] @ W_seed -> Wcomb cols 256..767 ----------------
__global__ __launch_bounds__(256) void wc_kernel(const float* __restrict__ Wcat,
                                                 const float* __restrict__ Wseed,
                                                 unsigned short* __restrict__ Wcomb) {
    __shared__ float sa[64][68];
    __shared__ float sbt[64][68];
    int tid = threadIdx.x;
    int to = blockIdx.y * 64;
    int tc = blockIdx.x * 64;
    int tx = tid & 15, ty = tid >> 4;
    float acc[4][4] = {};
    for (int kt = 0; kt < 256; kt += 64) {
        __syncthreads();
        #pragma unroll
        for (int r = 0; r < 4; ++r) {
            int oo = r * 16 + ty;
            float4 v = *(const float4*)(Wcat + (size_t)(to + oo) * 512 + 256 + kt + tx * 4);
            sa[oo][tx * 4 + 0] = v.x;
            sa[oo][tx * 4 + 1] = v.y;
            sa[oo][tx * 4 + 2] = v.z;
            sa[oo][tx * 4 + 3] = v.w;
            float4 u = *(const float4*)(Wseed + (size_t)(kt + oo) * 512 + tc + tx * 4);
            sbt[oo][tx * 4 + 0] = u.x;
            sbt[oo][tx * 4 + 1] = u.y;
            sbt[oo][tx * 4 + 2] = u.z;
            sbt[oo][tx * 4 + 3] = u.w;
        }
        __syncthreads();
        for (int k = 0; k < 64; ++k) {
            float a[4], bb[4];
            #pragma unroll
            for (int i = 0; i < 4; ++i) a[i] = sa[ty * 4 + i][k];
            #pragma unroll
            for (int j = 0; j < 4; ++j) bb[j] = sbt[k][tx * 4 + j];
            #pragma unroll
            for (int i = 0; i < 4; ++i)
                #pragma unroll
                for (int j = 0; j < 4; ++j)
                    acc[i][j] = fmaf(a[i], bb[j], acc[i][j]);
        }
    }
    #pragma unroll
    for (int i = 0; i < 4; ++i)
        #pragma unroll
        for (int j = 0; j < 4; ++j)
            Wcomb[(size_t)(to + ty * 4 + i) * KTOT + 256 + tc + tx * 4 + j] = f2bf(acc[i][j]);
}

// ---------------- K3b: W1 = W_concat[:, :256] -> Wcomb cols 0..255 ----------------
__global__ __launch_bounds__(256) void w1_kernel(const float* __restrict__ Wcat,
                                                 unsigned short* __restrict__ Wcomb) {
    int gid = blockIdx.x * 256 + threadIdx.x;  // 65536
    int o = gid >> 8, c = gid & 255;
    Wcomb[(size_t)o * KTOT + c] = f2bf(Wcat[(size_t)o * 512 + c]);
}

// ---------------- K3c: b_eff = W2 @ b_seed + b_concat (parallel: 1 block per output) ----------------
__global__ __launch_bounds__(64) void beff_kernel(const float* __restrict__ Wcat,
                                                  const float* __restrict__ bseed,
                                                  const float* __restrict__ bcat,
                                                  float* __restrict__ beff) {
    int o = blockIdx.x;
    int l = threadIdx.x;
    float4 w = *(const float4*)(Wcat + (size_t)o * 512 + 256 + l * 4);
    float4 bb = *(const float4*)(bseed + l * 4);
    float acc = __fmul_rn(w.x, bb.x);
    acc = fmaf(w.y, bb.y, acc);
    acc = fmaf(w.z, bb.z, acc);
    acc = fmaf(w.w, bb.w, acc);
    #pragma unroll
    for (int off = 32; off > 0; off >>= 1)
        acc += __shfl_down(acc, off);
    if (l == 0) beff[o] = acc + bcat[o];
}

// ---------------- K4: fused merge + gather + GEMM ----------------
// out[b](256 x 4096) = Wcomb(256x768) @ X(768x4096) + b_eff
// block tile 128(M) x 32(N), BK=64, 4 waves. grid (128, 2, 4)
__global__ __launch_bounds__(256) void fused_gemm_kernel(
        const unsigned short* __restrict__ Wcomb,
        const float* __restrict__ seed,
        const unsigned short* __restrict__ refT,
        const float* __restrict__ pval,
        const int* __restrict__ pidx,
        const float* __restrict__ beff,
        float* __restrict__ out) {
    __shared__ __align__(16) unsigned short sA[128][72];
    __shared__ __align__(16) unsigned short sB[32][72];
    __shared__ int sIdx[32];
    __shared__ float sBias[128];

    int tid = threadIdx.x;
    int b = blockIdx.z;
    int m0 = blockIdx.y * 128;
    int s0 = blockIdx.x * 32;
    if (tid < 32) {
        // merge 4 chunk-partials; disjoint ascending index ranges -> (val,idx) min
        int qs = b * S_ + s0 + tid;
        float v = pval[qs * 4 + 0];
        int x = pidx[qs * 4 + 0];
        #pragma unroll
        for (int c = 1; c < 4; ++c) {
            float vv = pval[qs * 4 + c];
            int xx = pidx[qs * 4 + c];
            if (vv < v || (vv == v && xx < x)) { v = vv; x = xx; }
        }
        sIdx[tid] = x & (NC - 1);   // defensive clamp: OOB gather impossible
    }
    if (tid < 128) sBias[tid] = beff[m0 + tid];

    int lane = tid & 63;
    int w = tid >> 6;
    int ln = lane & 15;
    int quad = lane >> 4;
    int q8 = quad * 8;

    f32x4 acc[2][2];
    #pragma unroll
    for (int i = 0; i < 2; ++i)
        #pragma unroll
        for (int j = 0; j < 2; ++j)
            acc[i][j] = (f32x4){0.f, 0.f, 0.f, 0.f};

    for (int ks = 0; ks < 12; ++ks) {
        int k0 = ks * 64;
        __syncthreads();
        #pragma unroll
        for (int i = 0; i < 4; ++i) {
            int ch = tid + 256 * i;
            int mm = ch >> 3;
            int kk8 = (ch & 7) << 3;
            *(short8*)&sA[mm][kk8] =
                *(const short8*)(Wcomb + (size_t)(m0 + mm) * KTOT + k0 + kk8);
        }
        if (k0 < 256) {
            int n = tid & 31;
            int kk8 = (tid >> 5) << 3;
            const float* sp = seed + ((size_t)b * CS + k0 + kk8) * S_ + s0 + n;
            unsigned short tmp[8];
            #pragma unroll
            for (int r = 0; r < 8; ++r)
                tmp[r] = f2bf(sp[(size_t)r * S_]);
            *(short8*)&sB[n][kk8] = *(const short8*)tmp;
        } else {
            int n = tid >> 3;
            int kk8 = (tid & 7) << 3;
            const unsigned short* gp =
                refT + ((size_t)b * NC + sIdx[n]) * C_ + (k0 - 256) + kk8;
            *(short8*)&sB[n][kk8] = *(const short8*)gp;
        }
        __syncthreads();
        #pragma unroll
        for (int kf = 0; kf < 2; ++kf) {
            short8 af[2], bfr[2];
            #pragma unroll
            for (int i = 0; i < 2; ++i)
                af[i] = *(const short8*)&sA[w * 32 + i * 16 + ln][kf * 32 + q8];
            #pragma unroll
            for (int j = 0; j < 2; ++j)
                bfr[j] = *(const short8*)&sB[j * 16 + ln][kf * 32 + q8];
            #pragma unroll
            for (int i = 0; i < 2; ++i)
                #pragma unroll
                for (int j = 0; j < 2; ++j)
                    acc[i][j] = __builtin_amdgcn_mfma_f32_16x16x32_bf16(af[i], bfr[j], acc[i][j], 0, 0, 0);
        }
    }

    #pragma unroll
    for (int i = 0; i < 2; ++i) {
        int mb = w * 32 + i * 16 + quad * 4;
        #pragma unroll
        for (int j = 0; j < 2; ++j) {
            int col = s0 + j * 16 + ln;
            #pragma unroll
            for (int r = 0; r < 4; ++r) {
                int m = mb + r;
                out[((size_t)b * CS + m0 + m) * S_ + col] = acc[i][j][r] + sBias[m];
            }
        }
    }
}

extern "C" void kernel_launch(void* const* d_in, const int* in_sizes, int n_in,
                              void* d_out, int out_size, void* d_ws, size_t ws_size,
                              hipStream_t stream) {
    const float* qxyz  = (const float*)d_in[0];
    const float* rxyz  = (const float*)d_in[1];
    const float* rfeat = (const float*)d_in[2];
    const float* seed  = (const float*)d_in[3];
    const float* Wseed = (const float*)d_in[4];
    const float* bseed = (const float*)d_in[5];
    const float* Wcat  = (const float*)d_in[6];
    const float* bcat  = (const float*)d_in[7];
    float* out = (float*)d_out;

    char* ws = (char*)d_ws;
    float* pval           = (float*)(ws);                        // 256 KB
    int* pidx             = (int*)(ws + 262144);                 // 256 KB
    float* beff           = (float*)(ws + 524288);               // 1 KB
    float4* refpk         = (float4*)(ws + 528384);              // 512 KB
    unsigned short* Wcomb = (unsigned short*)(ws + 1052672);     // 384 KB
    unsigned short* refT  = (unsigned short*)(ws + 1445888);     // 32 MB -> end 33.4 MB

    hipLaunchKernelGGL(pad_ref_kernel,        dim3(128),       dim3(256), 0, stream, rxyz, refpk);
    hipLaunchKernelGGL(argmin_partial_kernel, dim3(128, 4, 4), dim3(256), 0, stream,
                       qxyz, refpk, pval, pidx);
    hipLaunchKernelGGL(transpose_kernel,      dim3(128, 8, 4), dim3(256), 0, stream, rfeat, refT);
    hipLaunchKernelGGL(wc_kernel,             dim3(8, 4),      dim3(256), 0, stream, Wcat, Wseed, Wcomb);
    hipLaunchKernelGGL(w1_kernel,             dim3(256),       dim3(256), 0, stream, Wcat, Wcomb);
    hipLaunchKernelGGL(beff_kernel,           dim3(256),       dim3(64),  0, stream, Wcat, bseed, bcat, beff);
    hipLaunchKernelGGL(fused_gemm_kernel,     dim3(128, 2, 4), dim3(256), 0, stream,
                       Wcomb, seed, refT, pval, pidx, beff, out);
}